// Round 14
// baseline (154.198 us; speedup 1.0000x reference)
//
#include <hip/hip_runtime.h>
#include <stdint.h>

// Problem constants
#define DIMC   256
#define NHEADS 8
#define HD     32
#define BATCH  4
#define SEQ    2048
#define MTOT   (BATCH * SEQ)        // 8192 tokens
#define QKVN   (MTOT * HD * NHEADS) // 2097152 elements per q/k/v tensor
#define SCALE  0.17677669529663687f // 1/sqrt(32)
#define LOG2E  1.4426950408889634f
#define SCL2E  (SCALE * LOG2E)

typedef short bf16x8 __attribute__((ext_vector_type(8)));
typedef float f32x4  __attribute__((ext_vector_type(4)));

#if defined(__has_builtin)
#if __has_builtin(__builtin_amdgcn_exp2f)
#define EXP2F __builtin_amdgcn_exp2f
#else
#define EXP2F exp2f
#endif
#else
#define EXP2F exp2f
#endif

static __device__ __forceinline__ unsigned short f2bf(float f) {
    unsigned int u = __float_as_uint(f);
    u += 0x7fffu + ((u >> 16) & 1u);   // RNE
    return (unsigned short)(u >> 16);
}

static __device__ __forceinline__ unsigned int cvt2(float a, float b) {
#if defined(__has_builtin) && __has_builtin(__builtin_amdgcn_cvt_pk_bf16_f32)
    typedef __bf16 bf2 __attribute__((ext_vector_type(2)));
    bf2 v = __builtin_amdgcn_cvt_pk_bf16_f32(a, b);
    return __builtin_bit_cast(unsigned int, v);
#else
    return (unsigned int)f2bf(a) | ((unsigned int)f2bf(b) << 16);
#endif
}

// load 8 consecutive fp32 and pack to a bf16x8 fragment
static __device__ __forceinline__ bf16x8 ld8f_bf(const float* p) {
    float4 a0 = *(const float4*)p;
    float4 a1 = *(const float4*)(p + 4);
    uint4 pk;
    pk.x = cvt2(a0.x, a0.y); pk.y = cvt2(a0.z, a0.w);
    pk.z = cvt2(a1.x, a1.y); pk.w = cvt2(a1.z, a1.w);
    return __builtin_bit_cast(bf16x8, pk);
}

// ---------------------------------------------------------------------------
// QKV GEMM. 128x64 tile; W staged in TWO 16KB halves (LDS-diet: 17 KB total
// -> more blocks/CU under the small effective LDS occupancy pool).
// A-frags direct from global fp32 (cvt on the fly). q pre-scaled by
// SCALE*log2e; V stored transposed [bh][hd][seq] via in-LDS transpose.
// ---------------------------------------------------------------------------
__global__ __launch_bounds__(256) void gemm_qkv_kernel(
    const float* __restrict__ A,
    const float* __restrict__ W,
    const float* __restrict__ bias,
    unsigned short* __restrict__ qb,
    unsigned short* __restrict__ kb,
    unsigned short* __restrict__ vtb)
{
    // union: FW half-tile (16 KB) / TR transpose buffer (17 KB)
    __shared__ __align__(16) unsigned char SM[17408];
    unsigned short (*FW)[64][32] = (unsigned short (*)[64][32])SM;   // [4][64][32]
    float (*TR)[68] = (float (*)[68])SM;                              // [64][68]

    const int t    = threadIdx.x;
    const int wave = t >> 6;
    const int lane = t & 63;
    const int cg   = lane & 15;
    const int quad = lane >> 4;
    const int m0   = blockIdx.y * 128;
    const int n0   = blockIdx.x * 64;

    const float* Arow = A + (size_t)(m0 + wave * 16 + cg) * 256 + quad * 8;
    const int rsw = ((cg >> 1) & 3);   // read swizzle term

    f32x4 acc[2][4];
    #pragma unroll
    for (int s = 0; s < 2; s++)
        #pragma unroll
        for (int c = 0; c < 4; c++) acc[s][c] = (f32x4){0.f, 0.f, 0.f, 0.f};

    #pragma unroll
    for (int half = 0; half < 2; half++) {
        if (half) __syncthreads();        // prior half's reads complete
        {   // stage 4 k-chunks of the W tile (fp32 -> bf16, swizzled)
            int r  = t >> 2, cb = t & 3;
            int pc = (cb ^ ((r >> 1) & 3)) << 3;
            #pragma unroll
            for (int c4 = 0; c4 < 4; c4++)
                *(bf16x8*)&FW[c4][r][pc] =
                    ld8f_bf(W + (size_t)(n0 + r) * 256 + (half * 4 + c4) * 32 + cb * 8);
        }
        __syncthreads();

        #pragma unroll
        for (int c4 = 0; c4 < 4; c4++) {
            int chunk = half * 4 + c4;
            bf16x8 wf[4];
            #pragma unroll
            for (int c = 0; c < 4; c++)
                wf[c] = *(const bf16x8*)&FW[c4][c * 16 + cg][(quad ^ rsw) << 3];
            #pragma unroll
            for (int s = 0; s < 2; s++) {
                bf16x8 af = ld8f_bf(Arow + (size_t)s * 64 * 256 + chunk * 32);
                #pragma unroll
                for (int c = 0; c < 4; c++)
                    acc[s][c] = __builtin_amdgcn_mfma_f32_16x16x32_bf16(af, wf[c], acc[s][c], 0, 0, 0);
            }
        }
    }

    if (blockIdx.x >= 8) {
        // pure-V tile: transpose through LDS for coalesced Vt stores
        #pragma unroll
        for (int s = 0; s < 2; s++) {
            __syncthreads();   // FW reads / previous TR pass done
            #pragma unroll
            for (int c = 0; c < 4; c++) {
                int l = c * 16 + cg;              // local n
                float bv = bias[n0 + l];
                float4 vv;
                vv.x = acc[s][c][0] + bv; vv.y = acc[s][c][1] + bv;
                vv.z = acc[s][c][2] + bv; vv.w = acc[s][c][3] + bv;
                *(float4*)__builtin_assume_aligned(&TR[l][wave * 16 + quad * 4], 16) = vv;
            }
            __syncthreads();
            int l  = t >> 2;                      // local n 0..63
            int mm = (t & 3) << 4;                // m offset 0,16,32,48
            int n  = n0 + l;
            int h  = (n >> 5) & 7;
            int d  = n & 31;
            int b_ = m0 >> 11;
            int nn = (m0 & 2047) + s * 64 + mm;
            const float* tr = (const float*)__builtin_assume_aligned(&TR[l][mm], 16);
            float4 v0 = *(const float4*)(tr);
            float4 v1 = *(const float4*)(tr + 4);
            float4 v2 = *(const float4*)(tr + 8);
            float4 v3 = *(const float4*)(tr + 12);
            uint4 pk0, pk1;
            pk0.x = cvt2(v0.x, v0.y); pk0.y = cvt2(v0.z, v0.w);
            pk0.z = cvt2(v1.x, v1.y); pk0.w = cvt2(v1.z, v1.w);
            pk1.x = cvt2(v2.x, v2.y); pk1.y = cvt2(v2.z, v2.w);
            pk1.z = cvt2(v3.x, v3.y); pk1.w = cvt2(v3.z, v3.w);
            unsigned short* dst = vtb + ((size_t)((b_ * NHEADS + h) * HD + d)) * SEQ + nn;
            *(uint4*)dst       = pk0;
            *(uint4*)(dst + 8) = pk1;
        }
        return;
    }

    #pragma unroll
    for (int s = 0; s < 2; s++) {
        #pragma unroll
        for (int c = 0; c < 4; c++) {
            int n = n0 + c * 16 + cg;
            float bv = bias[n];
            int which = n >> 8;        // 0 q, 1 k
            int h     = (n >> 5) & 7;
            int d     = n & 31;
            #pragma unroll
            for (int rr = 0; rr < 4; rr++) {
                int m = m0 + s * 64 + wave * 16 + quad * 4 + rr;
                float val = acc[s][c][rr] + bv;
                int b_ = m >> 11;
                int nn = m & 2047;
                int bh = b_ * NHEADS + h;
                if (which == 0)
                    qb[((size_t)bh * SEQ + nn) * HD + d] = f2bf(val * SCL2E);
                else
                    kb[((size_t)bh * SEQ + nn) * HD + d] = f2bf(val);
            }
        }
    }
}

// ---------------------------------------------------------------------------
// Projection GEMM. 64x64 tile; W staged in two 16KB halves; fp32 store.
// ---------------------------------------------------------------------------
__global__ __launch_bounds__(256) void gemm_proj_kernel(
    const unsigned short* __restrict__ A,
    const float* __restrict__ W,
    const float* __restrict__ bias,
    float* __restrict__ outf)
{
    __shared__ __align__(16) unsigned short FW[4][64][32];   // 16 KB

    const int t    = threadIdx.x;
    const int wave = t >> 6;
    const int lane = t & 63;
    const int cg   = lane & 15;
    const int quad = lane >> 4;
    const int m0   = blockIdx.y * 64;
    const int n0   = blockIdx.x * 64;

    const unsigned short* Arow = A + (size_t)(m0 + wave * 16 + cg) * 256 + quad * 8;
    const int rsw = ((cg >> 1) & 3);

    f32x4 acc[4];
    #pragma unroll
    for (int c = 0; c < 4; c++) acc[c] = (f32x4){0.f, 0.f, 0.f, 0.f};

    #pragma unroll
    for (int half = 0; half < 2; half++) {
        if (half) __syncthreads();
        {
            int r  = t >> 2, cb = t & 3;
            int pc = (cb ^ ((r >> 1) & 3)) << 3;
            #pragma unroll
            for (int c4 = 0; c4 < 4; c4++)
                *(bf16x8*)&FW[c4][r][pc] =
                    ld8f_bf(W + (size_t)(n0 + r) * 256 + (half * 4 + c4) * 32 + cb * 8);
        }
        __syncthreads();

        #pragma unroll
        for (int c4 = 0; c4 < 4; c4++) {
            int chunk = half * 4 + c4;
            bf16x8 af = *(const bf16x8*)(Arow + chunk * 32);
            bf16x8 wf[4];
            #pragma unroll
            for (int c = 0; c < 4; c++)
                wf[c] = *(const bf16x8*)&FW[c4][c * 16 + cg][(quad ^ rsw) << 3];
            #pragma unroll
            for (int c = 0; c < 4; c++)
                acc[c] = __builtin_amdgcn_mfma_f32_16x16x32_bf16(af, wf[c], acc[c], 0, 0, 0);
        }
    }

    #pragma unroll
    for (int c = 0; c < 4; c++) {
        int n = n0 + c * 16 + cg;
        float bv = bias[n];
        #pragma unroll
        for (int rr = 0; rr < 4; rr++) {
            int m = m0 + wave * 16 + quad * 4 + rr;
            outf[(size_t)m * 256 + n] = acc[c][rr] + bv;
        }
    }
}

// ---------------------------------------------------------------------------
// Key-split MFMA flash attention, LDS-diet version (17.3 KB total).
// Block = 64 queries; 4 waves over disjoint 512-key ranges (fixed-max
// softmax -> partials sum). Bias folded via in-register one-hot QA +
// 448B KA7 LDS bias rows. Denominator via ones-column PV MFMA.
// P/PV processed in TWO passes of 2 query sub-tiles; per-wave P region is
// 4 KB (32 rows x 128B) with a chunk-XOR swizzle (phys16B = logical ^
// (cg&7)) that puts both b64 writes and b128 reads at the bank floor.
// Cross-wave fp32 exchange reuses the region in two 32-query passes.
// ---------------------------------------------------------------------------
__global__ __launch_bounds__(256) void attn_mfma_kernel(
    const unsigned short* __restrict__ Q,
    const unsigned short* __restrict__ K,
    const unsigned short* __restrict__ Vt,
    const float* __restrict__ table,
    unsigned short* __restrict__ AO)
{
    // per-wave 4224B region: P (32 rows x 64 u16, stride 128B) OR f32[32][33]
    __shared__ __align__(16) unsigned char SMEM[4][4224];    // 16.5 KB
    __shared__ __align__(16) unsigned short KA7[7][32];      // 448 B

    const int t    = threadIdx.x;
    const int wave = t >> 6;
    const int lane = t & 63;
    const int cg   = lane & 15;
    const int quad = lane >> 4;

    const int bid = blockIdx.x;
    const int qt  = bid & 31;
    const int bh  = bid >> 5;
    const int b   = bh >> 3;
    const int h   = bh & 7;
    const int q0  = qt * 64;

    if (t < 224) {
        int r = t >> 5, c = t & 31;
        float v = (c < 7) ? table[c - r + 6] * LOG2E : 0.f;
        KA7[r][c] = f2bf(v);
    }
    __syncthreads();

    const unsigned short* Kbase = K  + (size_t)bh * (SEQ * HD);
    const unsigned short* Vbase = Vt + (size_t)bh * (SEQ * HD);
    unsigned short* Pw = (unsigned short*)&SMEM[wave][0];
    const int csw = cg & 7;   // chunk swizzle

    bf16x8 qf[4], qfa[4];
    #pragma unroll
    for (int qi = 0; qi < 4; qi++) {
        qf[qi]  = *(const bf16x8*)(Q + (size_t)bh * (SEQ * HD) +
                                   (size_t)(q0 + qi * 16 + cg) * HD + quad * 8);
        int p = (q0 + qi * 16 + cg) % 7;
        #pragma unroll
        for (int i = 0; i < 8; i++)
            qfa[qi][i] = (quad == 0 && i == p) ? (short)0x3F80 : (short)0;
    }

    bf16x8 ones;
    #pragma unroll
    for (int i = 0; i < 8; i++) ones[i] = (short)0x3F80;

    f32x4 o[4][2], ol[4];
    #pragma unroll
    for (int qi = 0; qi < 4; qi++) {
        o[qi][0] = (f32x4){0.f, 0.f, 0.f, 0.f};
        o[qi][1] = (f32x4){0.f, 0.f, 0.f, 0.f};
        ol[qi]   = (f32x4){0.f, 0.f, 0.f, 0.f};
    }

    const int kstart = wave * (SEQ / 4);
    int kb7[4];
    #pragma unroll
    for (int jt = 0; jt < 4; jt++) kb7[jt] = (kstart + jt * 16 + cg) % 7;

    #pragma unroll 2
    for (int jj = 0; jj < SEQ / 4; jj += 64) {
        const int j0 = kstart + jj;

        bf16x8 kf[4], kfa[4];
        #pragma unroll
        for (int jt = 0; jt < 4; jt++) {
            kf[jt]  = *(const bf16x8*)(Kbase + (size_t)(j0 + jt * 16 + cg) * HD + quad * 8);
            kfa[jt] = *(const bf16x8*)&KA7[kb7[jt]][quad * 8];
        }
        bf16x8 vf[2][2];
        #pragma unroll
        for (int kt = 0; kt < 2; kt++)
            #pragma unroll
            for (int dt = 0; dt < 2; dt++)
                vf[kt][dt] = *(const bf16x8*)(Vbase + (size_t)(dt * 16 + cg) * SEQ +
                                              j0 + kt * 32 + quad * 8);

        // two passes of 2 query sub-tiles: S -> exp -> P(LDS, 4KB) -> PV
        #pragma unroll
        for (int half = 0; half < 2; half++) {
            f32x4 s[2][4];
            #pragma unroll
            for (int qh = 0; qh < 2; qh++) {
                int qi = half * 2 + qh;
                #pragma unroll
                for (int jt = 0; jt < 4; jt++) {
                    s[qh][jt] = __builtin_amdgcn_mfma_f32_16x16x32_bf16(
                        kfa[jt], qfa[qi], (f32x4){0.f, 0.f, 0.f, 0.f}, 0, 0, 0);
                    s[qh][jt] = __builtin_amdgcn_mfma_f32_16x16x32_bf16(
                        kf[jt], qf[qi], s[qh][jt], 0, 0, 0);
                }
            }
            #pragma unroll
            for (int qh = 0; qh < 2; qh++) {
                #pragma unroll
                for (int jt = 0; jt < 4; jt++) {
                    float p0 = EXP2F(s[qh][jt][0]);
                    float p1 = EXP2F(s[qh][jt][1]);
                    float p2 = EXP2F(s[qh][jt][2]);
                    float p3 = EXP2F(s[qh][jt][3]);
                    uint2 w;
                    w.x = cvt2(p0, p1);
                    w.y = cvt2(p2, p3);
                    // row qh*16+cg; logical chunk 2jt+(quad>>1); phys = ^csw
                    int pc = (2 * jt + (quad >> 1)) ^ csw;
                    *(uint2*)(Pw + (qh * 16 + cg) * 64 + pc * 8 + (quad & 1) * 4) = w;
                }
            }
            __builtin_amdgcn_s_waitcnt(0xC07F);   // lgkmcnt(0): wave-local RAW

            #pragma unroll
            for (int qh = 0; qh < 2; qh++) {
                int qi = half * 2 + qh;
                bf16x8 pa0 = *(const bf16x8*)(Pw + (qh * 16 + cg) * 64 + ((quad ^ csw) << 3));
                bf16x8 pa1 = *(const bf16x8*)(Pw + (qh * 16 + cg) * 64 + (((4 + quad) ^ csw) << 3));
                o[qi][0] = __builtin_amdgcn_mfma_f32_16x16x32_bf16(pa0, vf[0][0], o[qi][0], 0, 0, 0);
                o[qi][0] = __builtin_amdgcn_mfma_f32_16x16x32_bf16(pa1, vf[1][0], o[qi][0], 0, 0, 0);
                o[qi][1] = __builtin_amdgcn_mfma_f32_16x16x32_bf16(pa0, vf[0][1], o[qi][1], 0, 0, 0);
                o[qi][1] = __builtin_amdgcn_mfma_f32_16x16x32_bf16(pa1, vf[1][1], o[qi][1], 0, 0, 0);
                ol[qi]   = __builtin_amdgcn_mfma_f32_16x16x32_bf16(pa0, ones, ol[qi], 0, 0, 0);
                ol[qi]   = __builtin_amdgcn_mfma_f32_16x16x32_bf16(pa1, ones, ol[qi], 0, 0, 0);
            }
        }

        #pragma unroll
        for (int jt = 0; jt < 4; jt++)
            kb7[jt] = (kb7[jt] == 6) ? 0 : kb7[jt] + 1;
    }

    // cross-wave exchange: two passes of 32 queries; region reused as
    // f32[32][33] per wave (col 32 = partial l)
    #pragma unroll
    for (int p = 0; p < 2; p++) {
        __syncthreads();    // previous use of region complete (all waves)
        float* OPw = (float*)&SMEM[wave][0];
        #pragma unroll
        for (int qh = 0; qh < 2; qh++) {
            int qi = p * 2 + qh;
            #pragma unroll
            for (int dt = 0; dt < 2; dt++)
                #pragma unroll
                for (int rr = 0; rr < 4; rr++)
                    OPw[(qh * 16 + quad * 4 + rr) * 33 + dt * 16 + cg] = o[qi][dt][rr];
            if (cg == 0) {
                #pragma unroll
                for (int rr = 0; rr < 4; rr++)
                    OPw[(qh * 16 + quad * 4 + rr) * 33 + 32] = ol[qi][rr];
            }
        }
        __syncthreads();
        // reduce: thread t -> local query t>>3 (0..31), dims (t&7)*4..+3
        int ql = t >> 3;
        int d0 = (t & 7) << 2;
        float l = 0.f;
        float ov[4] = {0.f, 0.f, 0.f, 0.f};
        #pragma unroll
        for (int w = 0; w < 4; w++) {
            const float* OPx = (const float*)&SMEM[w][0];
            l += OPx[ql * 33 + 32];
            #pragma unroll
            for (int i = 0; i < 4; i++) ov[i] += OPx[ql * 33 + d0 + i];
        }
        float inv = 1.f / l;
        uint2 pk;
        pk.x = cvt2(ov[0] * inv, ov[1] * inv);
        pk.y = cvt2(ov[2] * inv, ov[3] * inv);
        *(uint2*)(AO + ((size_t)(b * SEQ + q0 + p * 32 + ql)) * DIMC + h * HD + d0) = pk;
    }
}

// ---------------------------------------------------------------------------
extern "C" void kernel_launch(void* const* d_in, const int* in_sizes, int n_in,
                              void* d_out, int out_size, void* d_ws, size_t ws_size,
                              hipStream_t stream) {
    const float* x      = (const float*)d_in[0]; // (4,2048,256)
    const float* qkv_w  = (const float*)d_in[1]; // (768,256)
    const float* qkv_b  = (const float*)d_in[2]; // (768)
    const float* proj_w = (const float*)d_in[3]; // (256,256)
    const float* proj_b = (const float*)d_in[4]; // (256)
    const float* table  = (const float*)d_in[5]; // (104)
    float* out = (float*)d_out;                  // (4,2048,256) fp32

    unsigned short* ws   = (unsigned short*)d_ws;
    unsigned short* qb   = ws;                         // [bh][seq][32] bf16 (pre-scaled)
    unsigned short* kb   = qb  + (size_t)QKVN;
    unsigned short* vtb  = kb  + (size_t)QKVN;         // [bh][32][seq]
    unsigned short* ao   = vtb + (size_t)QKVN;         // [B*seq][256]

    // 1) QKV GEMM (LDS-diet: 17 KB)
    gemm_qkv_kernel<<<dim3(12, 64), 256, 0, stream>>>(
        x, qkv_w, qkv_b, qb, kb, vtb);

    // 2) key-split MFMA flash attention (LDS-diet: 17.3 KB, swizzled P)
    attn_mfma_kernel<<<dim3(BATCH * NHEADS * (SEQ / 64)), 256, 0, stream>>>(
        qb, kb, vtb, table, ao);

    // 3) output projection (LDS-diet: 16 KB)
    gemm_proj_kernel<<<dim3(4, 128), 256, 0, stream>>>(
        ao, proj_w, proj_b, out);
}